// Round 3
// baseline (135.053 us; speedup 1.0000x reference)
//
#include <hip/hip_runtime.h>
#include <math.h>

// Elementwise OxideModel 'second' branch.
// N = 2^24 fp32 in -> fp32 out, 4 broadcast scalars.
// Memory-bound target: ~128 MB @ ~6.3 TB/s => ~21 us.

struct Scalars {
    float E;      // clipped exp(E_param)*1000
    float U;      // sqrt(V)
    float K;
    float expK;
    float xT;     // E / sT
    float fsT;    // K - E/sT
    float coef;   // (1/3) * exp(fsT/2)
    float IsT;    // integral(sT)
};

// Ei(-x) for x > 0, mirroring reference _expi_impl (z = -x).
// 'e' must be expf(-x) (reused from caller; only consumed when x > 1).
__device__ __forceinline__ float expi_negx(float x, float e) {
    if (x <= 1.0f) {
        // small-x series branch (dead for the real input range x in [6.25,16.7],
        // kept for faithfulness; s_cbranch_execz skips it when no lane enters)
        float xs = fminf(fmaxf(x, 1e-30f), 1.0f);
        float term = 1.0f;
        float s = 0.0f;
#pragma unroll 1
        for (int k = 1; k <= 25; ++k) {
            term = term * (-xs) / (float)k;
            s += term / (float)k;
        }
        return 0.5772156649015329f + logf(xs) + s;
    } else {
        // Abramowitz & Stegun 5.1.56 rational approx; keep the two separate
        // divides to match reference rounding (cancellation downstream
        // amplifies ULP differences ~10-30x).
        float P = (((x + 8.5733287401f) * x + 18.0590169730f) * x + 8.6347608925f) * x
                  + 0.2677737343f;
        float Q = (((x + 9.5733223454f) * x + 25.6329561486f) * x + 21.0996530827f) * x
                  + 3.9584969228f;
        return -(e / x) * (P / Q);
    }
}

__device__ __forceinline__ Scalars make_scalars(float gshift, float E_param,
                                                float T_max_delta, float V_max) {
    Scalars s;
    s.E = fminf(fmaxf(expf(E_param) * 1000.0f, 1e-10f), 1e10f);
    float V = fminf(fmaxf(expf(V_max) * 1.0f, 1e-10f), 1e10f);
    float T_max = 500.0f + 50.0f * tanhf(T_max_delta * 1.0f) + gshift;
    float sT = fmaxf(T_max, 1e-10f);
    s.U = sqrtf(V);
    s.K = s.E / sT + (2.0f / 3.0f) * logf(1.5f * s.E * s.U / (sT * sT));
    s.expK = expf(s.K);
    s.xT = s.E / sT;
    s.fsT = s.K - s.xT;
    s.coef = (1.0f / 3.0f) * expf(s.fsT * 0.5f);
    float eT = expf(-s.xT);
    float eiT = expi_negx(s.xT, eT);
    s.IsT = s.expK * (sT * eT + s.E * eiT);
    return s;
}

__device__ __forceinline__ float compute_one(float t, const Scalars& s) {
    float st = fmaxf(t, 1e-10f);
    float x = s.E / st;                 // E/st  (= -z)
    float e = expf(-x);                 // shared: integral's exp(-E/t) and expi's exp(-xl)
    float ei = expi_negx(x, e);         // Ei(-E/st)
    float Ist = s.expK * (st * e + s.E * ei);   // integral(st)
    float result = Ist - s.IsT;
    float exp_arg = (s.K - x) - s.fsT;  // f(st) - f(sT)
    exp_arg = fminf(fmaxf(exp_arg, -100.0f), 100.0f);
    float inner = s.U - s.coef * result;
    float r = fmaxf(inner, 0.0f);
    return expf(exp_arg) * (r * r);
}

extern "C" __global__ void __launch_bounds__(256, 4)
oxide_kernel(const float* __restrict__ in,
             const float* __restrict__ p_gs,
             const float* __restrict__ p_E,
             const float* __restrict__ p_Td,
             const float* __restrict__ p_V,
             float* __restrict__ out, int n) {
    // Per-thread scalar preamble; amortized over the grid-stride loop
    // (2048x256 grid, 2^22 float4 elems -> 8 iters/thread => ~5 ops/elem overhead).
    Scalars s = make_scalars(p_gs[0], p_E[0], p_Td[0], p_V[0]);

    int tid = blockIdx.x * blockDim.x + threadIdx.x;
    int stride = gridDim.x * blockDim.x;
    int n4 = n >> 2;
    const float4* __restrict__ in4 = (const float4*)in;
    float4* __restrict__ out4 = (float4*)out;

    for (int i = tid; i < n4; i += stride) {
        float4 v = in4[i];
        float4 o;
        o.x = compute_one(v.x, s);
        o.y = compute_one(v.y, s);
        o.z = compute_one(v.z, s);
        o.w = compute_one(v.w, s);
        out4[i] = o;
    }
    // tail (n not divisible by 4) — dead for N=2^24 but kept for generality
    int base = n4 << 2;
    for (int i = base + tid; i < n; i += stride) {
        out[i] = compute_one(in[i], s);
    }
}

extern "C" void kernel_launch(void* const* d_in, const int* in_sizes, int n_in,
                              void* d_out, int out_size, void* d_ws, size_t ws_size,
                              hipStream_t stream) {
    const float* in = (const float*)d_in[0];
    const float* gs = (const float*)d_in[1];
    const float* Ep = (const float*)d_in[2];
    const float* Td = (const float*)d_in[3];
    const float* Vm = (const float*)d_in[4];
    float* out = (float*)d_out;
    int n = in_sizes[0];

    const int threads = 256;
    const int blocks = 2048;  // grid-stride; 8 float4 iters/thread at N=2^24
    oxide_kernel<<<blocks, threads, 0, stream>>>(in, gs, Ep, Td, Vm, out, n);
}

// Round 5
// 121.045 us; speedup vs baseline: 1.1157x; 1.1157x over previous
//
#include <hip/hip_runtime.h>
#include <math.h>

// Elementwise OxideModel 'second' branch, restructured.
// N = 2^24 fp32 in -> fp32 out. Measured R3: 49 us, VALU-bound (73% VALUBusy,
// 26% HBM). This version cuts VALU ~3x via:
//   st*e + E*Ei(-x) == st*e*(Q-P)/Q   (Q-P folded at compile time; kills the
//                                      runtime cancellation AND the e/x divide)
//   exp(f(st)-f(sT)) == exp(xT)*e     (kills the second expf)
//   v_rcp_f32 / v_exp_f32 raw ops     (kills IEEE-div expansions)
// Numeric budget: deviations ~1e-5 abs vs the bf16-quantum 0.0039 that passed.

struct Scalars {
    // fallback (x<=1 series) path — mirrors reference exactly
    float E, U, K, expK, coef, fsT, IsT;
    // restructured main-path constants
    float A;   // exp(xT)          : exp(f(st)-f(sT)) = A * e
    float B;   // coef * expK      : coef*Ist = B * st*e*R(x)
    float C;   // U + coef * IsT   : inner = C - B*st*e*R(x)
};

// Q - P of A&S 5.1.56 (x^4 cancels; computed in coefficient space)
__device__ __forceinline__ float poly_N(float x) {
    return fmaf(fmaf(fmaf(0.9999936053f, x, 7.5739391756f), x, 12.4648921902f),
                x, 3.6907231885f);
}
__device__ __forceinline__ float poly_Q(float x) {
    return fmaf(fmaf(fmaf((x + 9.5733223454f), x, 25.6329561486f), x,
                     21.0996530827f), x, 3.9584969228f);
}

__device__ __forceinline__ Scalars make_scalars(float gshift, float E_param,
                                                float T_max_delta, float V_max) {
    Scalars s;
    s.E = fminf(fmaxf(expf(E_param) * 1000.0f, 1e-10f), 1e10f);
    float V = fminf(fmaxf(expf(V_max), 1e-10f), 1e10f);
    float T_max = 500.0f + 50.0f * tanhf(T_max_delta) + gshift;
    float sT = fmaxf(T_max, 1e-10f);
    s.U = sqrtf(V);
    float xT = s.E / sT;
    s.K = xT + (2.0f / 3.0f) * logf(1.5f * s.E * s.U / (sT * sT));
    s.expK = expf(s.K);
    s.fsT = s.K - xT;
    s.coef = (1.0f / 3.0f) * expf(s.fsT * 0.5f);
    float eT = expf(-xT);
    if (xT > 1.0f) {
        // restructured integral(sT): expK * sT * eT * (Q-P)/Q
        s.IsT = s.expK * sT * eT * (poly_N(xT) / poly_Q(xT));
    } else {
        // reference series branch (dead for bench params: xT = 10)
        float xs = fminf(fmaxf(xT, 1e-30f), 1.0f);
        float term = 1.0f, acc = 0.0f;
#pragma unroll 1
        for (int k = 1; k <= 25; ++k) {
            term = term * (-xs) / (float)k;
            acc += term / (float)k;
        }
        float ei = 0.5772156649015329f + logf(xs) + acc;
        s.IsT = s.expK * (sT * eT + s.E * ei);
    }
    s.A = expf(xT);
    s.B = s.coef * s.expK;
    s.C = s.U + s.coef * s.IsT;
    return s;
}

__device__ __forceinline__ float compute_one(float t, const Scalars& s) {
    float st = fmaxf(t, 1e-10f);
    float x = s.E * __builtin_amdgcn_rcpf(st);
    float e = __builtin_amdgcn_exp2f(x * -1.44269504088896f);  // exp(-x)
    if (x <= 1.0f) {
        // reference small-x path (uniformly dead for t in [300,800]: x>=6.25;
        // s_cbranch_execz skips it)
        float xs = fminf(fmaxf(x, 1e-30f), 1.0f);
        float term = 1.0f, acc = 0.0f;
#pragma unroll 1
        for (int k = 1; k <= 25; ++k) {
            term = term * (-xs) / (float)k;
            acc += term / (float)k;
        }
        float ei = 0.5772156649015329f + logf(xs) + acc;
        float e2 = expf(-x);
        float Ist = s.expK * (st * e2 + s.E * ei);
        float exp_arg = fminf(fmaxf((s.K - x) - s.fsT, -100.0f), 100.0f);
        float inner = s.U - s.coef * (Ist - s.IsT);
        float r = fmaxf(inner, 0.0f);
        return expf(exp_arg) * r * r;
    }
    // main path: out = exp(xT-x) * relu(U - coef*(Ist - IsT))^2
    //          = (A*e) * relu(C - B*st*e*(Q-P)/Q)^2
    float R = poly_N(x) * __builtin_amdgcn_rcpf(poly_Q(x));
    float inner = fmaf(-s.B * (st * e), R, s.C);
    float r = fmaxf(inner, 0.0f);
    return (s.A * e) * (r * r);
}

extern "C" __global__ void __launch_bounds__(256, 4)
oxide_kernel(const float* __restrict__ in,
             const float* __restrict__ p_gs,
             const float* __restrict__ p_E,
             const float* __restrict__ p_Td,
             const float* __restrict__ p_V,
             float* __restrict__ out, int n) {
    Scalars s = make_scalars(p_gs[0], p_E[0], p_Td[0], p_V[0]);

    int tid = blockIdx.x * blockDim.x + threadIdx.x;
    int stride = gridDim.x * blockDim.x;
    int n4 = n >> 2;
    const float4* __restrict__ in4 = (const float4*)in;
    float4* __restrict__ out4 = (float4*)out;

    for (int i = tid; i < n4; i += stride) {
        float4 v = in4[i];
        float4 o;
        o.x = compute_one(v.x, s);
        o.y = compute_one(v.y, s);
        o.z = compute_one(v.z, s);
        o.w = compute_one(v.w, s);
        out4[i] = o;
    }
    int base = n4 << 2;
    for (int i = base + tid; i < n; i += stride) {
        out[i] = compute_one(in[i], s);
    }
}

extern "C" void kernel_launch(void* const* d_in, const int* in_sizes, int n_in,
                              void* d_out, int out_size, void* d_ws, size_t ws_size,
                              hipStream_t stream) {
    const float* in = (const float*)d_in[0];
    const float* gs = (const float*)d_in[1];
    const float* Ep = (const float*)d_in[2];
    const float* Td = (const float*)d_in[3];
    const float* Vm = (const float*)d_in[4];
    float* out = (float*)d_out;
    int n = in_sizes[0];

    const int threads = 256;
    const int blocks = 2048;  // 8 float4 iters/thread at N=2^24
    oxide_kernel<<<blocks, threads, 0, stream>>>(in, gs, Ep, Td, Vm, out, n);
}